// Round 17
// baseline (92.735 us; speedup 1.0000x reference)
//
#include <hip/hip_runtime.h>
#include <hip/hip_bf16.h>
#include <cstdint>
#include <cstddef>

#define A_DIM 128
#define T_DIM 2048
#define F_DIM 128
#define RBF_DIM 16
#define KDD 2048              // K-span per dd block (128 atoms x 16 rbf)
#define VT_LD 18432           // Vt row stride = 9 * KDD
#define NKG 32                // K-groups (A_DIM / 4) — R13 best config
#define BT 64                 // t-span per gemm block

typedef __attribute__((ext_vector_type(8))) short short8;
typedef __attribute__((ext_vector_type(4))) float f32x4;
typedef __attribute__((ext_vector_type(4))) unsigned int u32x4;

__device__ __forceinline__ float silu_f(float x) {
    return x / (1.0f + __expf(-x));
}

// f2bf (RNE bit-twiddle) for build_vt; gemm A-build uses v_cvt_pk_bf16_f32
// (also RNE). Do NOT swap for __float2bfloat16.
__device__ __forceinline__ unsigned short f2bf(float x) {
    union { float f; unsigned u; } v; v.f = x;
    unsigned r = v.u + 0x7FFFu + ((v.u >> 16) & 1u);
    return (unsigned short)(r >> 16);
}

// async global->LDS, 16 B per lane; LDS dest is wave-uniform base + lane*16.
__device__ __forceinline__ void gl_lds16(const void* g, void* l) {
    __builtin_amdgcn_global_load_lds(
        (const __attribute__((address_space(1))) void*)g,
        (__attribute__((address_space(3))) void*)l, 16, 0, 0);
}

// Grid-stride float4 zero (fallback path only; plain path zeroes in gemm).
__global__ void zero_kernel(float4* __restrict__ p, int n4) {
    const int stride = gridDim.x * blockDim.x;
    const float4 z = {0.f, 0.f, 0.f, 0.f};
    for (int i = blockIdx.x * blockDim.x + threadIdx.x; i < n4; i += stride)
        p[i] = z;
}

// Fused MLP, retiled for w3 traffic: block = 32 atoms x 256 cols.
// Old tiling read the full 1 MB w3i per block (96 blocks = 96 MB HBM — the
// largest memory consumer in the pipeline). Now each block reads 128k x 256c
// = 128 KB -> 12 MB total. Layers 1/2 are recomputed per c-block (8x, ~100M
// FMA total — negligible); per-output k-ascending FMA chains are identical
// to the R13 version -> bitwise-identical rbfws.
// grid (A/32 = 4, 2048/256 = 8, 3), block 512. LDS 48 KB.
__global__ void mlp_fused_kernel(const float* __restrict__ feat0,
                                 const float* __restrict__ w1, const float* __restrict__ b1,
                                 const float* __restrict__ w2, const float* __restrict__ b2,
                                 const float* __restrict__ w3, const float* __restrict__ b3,
                                 float* __restrict__ rbfws) {
    __shared__ float inv_s[32 * F_DIM];   // 16 KB
    __shared__ float h_s[32 * F_DIM];     // 16 KB
    __shared__ float h2_s[32 * F_DIM];    // 16 KB
    const int i  = blockIdx.z;
    const int a0 = blockIdx.x * 32;
    const int c0 = blockIdx.y * 256;
    const int tid = threadIdx.x;
    const int f  = tid & 127;
    const int la = tid >> 7;              // 0..3

    // load inv for 32 atoms (4096 floats over 512 threads)
    #pragma unroll
    for (int j = 0; j < 8; ++j) {
        const int idx = j * 512 + tid;
        inv_s[idx] = feat0[(a0 + (idx >> 7)) * F_DIM + (idx & 127)];
    }
    __syncthreads();

    // layer 1: 8 atoms per thread (a = la + 4*j), output h_s[a*128+f]
    const float* w1i = w1 + (size_t)i * F_DIM * F_DIM;
    #pragma unroll
    for (int j = 0; j < 8; ++j) {
        const int a = la + 4 * j;
        float x = b1[i * F_DIM + f];
        #pragma unroll 8
        for (int k = 0; k < F_DIM; ++k)
            x = fmaf(inv_s[a * F_DIM + k], w1i[k * F_DIM + f], x);
        h_s[a * F_DIM + f] = silu_f(x);
    }
    __syncthreads();

    // layer 2
    const float* w2i = w2 + (size_t)i * F_DIM * F_DIM;
    #pragma unroll
    for (int j = 0; j < 8; ++j) {
        const int a = la + 4 * j;
        float y = b2[i * F_DIM + f];
        #pragma unroll 8
        for (int k = 0; k < F_DIM; ++k)
            y = fmaf(h_s[a * F_DIM + k], w2i[k * F_DIM + f], y);
        h2_s[a * F_DIM + f] = silu_f(y);
    }
    __syncthreads();

    // layer 3: thread -> atom-quad aq = tid>>6 (atoms 4aq..4aq+3),
    // cols c = c0 + (tid&63)*4. Same val[4][4] k-ascending chain as R13.
    const int aq = tid >> 6;
    const int c  = c0 + (tid & 63) * 4;
    const float* w3i = w3 + (size_t)i * F_DIM * 2048;
    float val[4][4];
    #pragma unroll
    for (int a = 0; a < 4; ++a) {
        #pragma unroll
        for (int cc = 0; cc < 4; ++cc)
            val[a][cc] = b3[i * 2048 + c + cc];
    }
    for (int k = 0; k < F_DIM; ++k) {
        const float4 w = *reinterpret_cast<const float4*>(&w3i[(size_t)k * 2048 + c]);
        #pragma unroll
        for (int a = 0; a < 4; ++a) {
            const float h = h2_s[(aq * 4 + a) * F_DIM + k];
            val[a][0] = fmaf(h, w.x, val[a][0]);
            val[a][1] = fmaf(h, w.y, val[a][1]);
            val[a][2] = fmaf(h, w.z, val[a][2]);
            val[a][3] = fmaf(h, w.w, val[a][3]);
        }
    }
    const float inv_rbf = 0.25f;  // 1/sqrt(16)
    #pragma unroll
    for (int a = 0; a < 4; ++a) {
        float4 o;
        o.x = val[a][0] * inv_rbf;
        o.y = val[a][1] * inv_rbf;
        o.z = val[a][2] * inv_rbf;
        o.w = val[a][3] * inv_rbf;
        *reinterpret_cast<float4*>(&rbfws[((size_t)i * A_DIM + a0 + aq * 4 + a) * 2048 + c]) = o;
    }
}

// Build Vt[f][k] bf16, k = dd*2048 + n*16 + r. (R4-exact.)
__global__ void build_vt_kernel(const float* __restrict__ feat0,
                                const float* __restrict__ feat1,
                                const float* __restrict__ feat2,
                                const float* __restrict__ rbfws,
                                unsigned short* __restrict__ Vt) {
    const int n  = blockIdx.x;
    const int dd = blockIdx.y;
    const int f  = threadIdx.x;

    int i, d;
    float fv;
    if (dd == 0)      { i = 0; d = 0;      fv = feat0[n * F_DIM + f]; }
    else if (dd < 4)  { i = 1; d = dd - 1; fv = feat1[(n * F_DIM + f) * 3 + d]; }
    else              { i = 2; d = dd - 4; fv = feat2[(n * F_DIM + f) * 5 + d]; }

    const float* rb = rbfws + ((size_t)(i * A_DIM + n) * RBF_DIM) * F_DIM + f;
    unsigned short* vp = Vt + (size_t)f * VT_LD + (size_t)dd * KDD + n * 16;
    #pragma unroll
    for (int r = 0; r < RBF_DIM; ++r)
        vp[r] = f2bf(fv * rb[(size_t)r * F_DIM]);
}

// MFMA GEMM — R13-exact (best measured: 63.7 us total). LDS-staged B + sph,
// monolithic dd-loop, zero-in-prologue, wave tile 32t x 64f.
// R15 LESSON: do NOT fuse heavy epilogue code here (regalloc collapse).
// grid (32 mt, 32 kg), block 256 = 4 waves in 2x2.
template<int MODE>
__global__ void __launch_bounds__(256) gemm_kernel(
        const float* __restrict__ sph0, const float* __restrict__ sph1,
        const float* __restrict__ sph2, const float* __restrict__ radial,
        const unsigned short* __restrict__ Vt,
        float* __restrict__ outbuf,
        float* __restrict__ dout, int out_n4) {
    __shared__ unsigned short b_s[F_DIM * 64];   // 16 KB: [f][chunk^(f&7)] 8-elem chunks
    __shared__ float sph_s[4 * BT];              // 1 KB: [nn][tt]

    const int tid  = threadIdx.x;
    const int lane = tid & 63;
    const int w    = tid >> 6;
    const int wr   = w >> 1;            // wave row (t)
    const int wc   = w & 1;             // wave col (f)
    const int t0   = blockIdx.x * BT + wr * 32;
    const int n0   = blockIdx.y * 4;
    const int kq   = lane >> 4;         // 0..3
    const int lf   = lane & 15;

    // Prologue: zero this block's slice of d_out (plain path only).
    if (MODE == 0) {
        const int bid = blockIdx.y * gridDim.x + blockIdx.x;     // 0..1023
        const float4 z = {0.f, 0.f, 0.f, 0.f};
        float4* zp = (float4*)dout;
        #pragma unroll
        for (int q = 0; q < 8; ++q) {
            const int idx = bid * 2048 + q * 256 + tid;
            if (idx < out_n4) zp[idx] = z;
        }
    }

    // radial is dd-invariant: preload once to regs.
    // k_local = 32*ks + 8*kq + j -> atom n0 + 2*ks + (kq>>1), r = (kq&1)*8 + j.
    f32x4 rad[2][2][2];
    #pragma unroll
    for (int m = 0; m < 2; ++m) {
        const int t = t0 + 16 * m + lf;
        #pragma unroll
        for (int ks = 0; ks < 2; ++ks) {
            const int n = n0 + 2 * ks + (kq >> 1);
            const float* rp = radial + ((size_t)n * T_DIM + t) * 16 + (kq & 1) * 8;
            rad[m][ks][0] = *reinterpret_cast<const f32x4*>(rp);
            rad[m][ks][1] = *reinterpret_cast<const f32x4*>(rp + 4);
        }
    }

    // B staging source: per issue q, row f = q*32 + tid/8, chunk c' = (tid%8)^((tid/8)&7)
    const int fs_row = tid >> 3;
    const int cs     = (tid & 7) ^ ((tid >> 3) & 7);
    const unsigned short* gsrc0 = Vt + (size_t)fs_row * VT_LD + n0 * 16 + cs * 8;
    // sph staging: thread tid -> sph_s[nn*BT+tt]
    const int nn_s = tid >> 6;
    const int tt_s = tid & 63;
    const size_t sph_tbase = (size_t)(n0 + nn_s) * T_DIM + blockIdx.x * BT + tt_s;

    f32x4 acc[2][4];
    #pragma unroll
    for (int m = 0; m < 2; ++m)
        #pragma unroll
        for (int nf = 0; nf < 4; ++nf)
            acc[m][nf] = (f32x4){0.f, 0.f, 0.f, 0.f};

    #pragma unroll 1
    for (int dd = 0; dd < 9; ++dd) {
        const float* sp; int smul, soff;
        if (dd == 0)     { sp = sph0; smul = 1; soff = 0; }
        else if (dd < 4) { sp = sph1; smul = 3; soff = dd - 1; }
        else             { sp = sph2; smul = 5; soff = dd - 4; }

        __syncthreads();   // previous iteration done reading LDS

        // stage B-tile: 4 issues x (256 lanes x 16 B) = 16 KB, linear LDS dest
        const size_t koff = (size_t)dd * KDD;
        #pragma unroll
        for (int q = 0; q < 4; ++q) {
            const unsigned short* gp = gsrc0 + koff + (size_t)(q * 32) * VT_LD;
            void* lp = (void*)((char*)b_s + q * 4096 + w * 1024);
            gl_lds16(gp, lp);
        }
        // stage sph tile (256 floats)
        sph_s[tid] = sp[sph_tbase * smul + soff];

        __syncthreads();   // drains vmcnt+lgkmcnt before s_barrier

        // B-fragments from LDS (swizzled read): chunk cw = 4*ks+kq at row f
        short8 bfr[2][4];
        #pragma unroll
        for (int ks = 0; ks < 2; ++ks) {
            #pragma unroll
            for (int nf = 0; nf < 4; ++nf) {
                const int f = wc * 64 + 16 * nf + lf;
                const int byte = f * 128 + (((ks * 4 + kq) ^ (lf & 7)) * 16);
                bfr[ks][nf] = *reinterpret_cast<const short8*>((const char*)b_s + byte);
            }
        }

        // A-fragments: 8 products + 4 v_cvt_pk_bf16_f32 (RNE), then MFMAs.
        #pragma unroll
        for (int m = 0; m < 2; ++m) {
            #pragma unroll
            for (int ks = 0; ks < 2; ++ks) {
                const float s = sph_s[(2 * ks + (kq >> 1)) * BT + wr * 32 + 16 * m + lf];
                unsigned int d0, d1, d2, d3;
                asm("v_cvt_pk_bf16_f32 %0, %1, %2" : "=v"(d0)
                    : "v"(s * rad[m][ks][0][0]), "v"(s * rad[m][ks][0][1]));
                asm("v_cvt_pk_bf16_f32 %0, %1, %2" : "=v"(d1)
                    : "v"(s * rad[m][ks][0][2]), "v"(s * rad[m][ks][0][3]));
                asm("v_cvt_pk_bf16_f32 %0, %1, %2" : "=v"(d2)
                    : "v"(s * rad[m][ks][1][0]), "v"(s * rad[m][ks][1][1]));
                asm("v_cvt_pk_bf16_f32 %0, %1, %2" : "=v"(d3)
                    : "v"(s * rad[m][ks][1][2]), "v"(s * rad[m][ks][1][3]));
                union { u32x4 u; short8 s8; } au;
                au.u = (u32x4){d0, d1, d2, d3};
                #pragma unroll
                for (int nf = 0; nf < 4; ++nf)
                    acc[m][nf] = __builtin_amdgcn_mfma_f32_16x16x32_bf16(
                        au.s8, bfr[ks][nf], acc[m][nf], 0, 0, 0);
            }
        }
    }

    // Epilogue. C/D layout col=lane&15, row=(lane>>4)*4+reg (HW-verified in R4).
    float* pb = (MODE == 0)
        ? outbuf + (size_t)blockIdx.y * (T_DIM * F_DIM)   // own slice, plain stores
        : outbuf;                                          // shared, atomics
    #pragma unroll
    for (int m = 0; m < 2; ++m) {
        #pragma unroll
        for (int nf = 0; nf < 4; ++nf) {
            const int f = wc * 64 + 16 * nf + lf;
            #pragma unroll
            for (int reg = 0; reg < 4; ++reg) {
                const int t = t0 + 16 * m + 4 * kq + reg;
                if (MODE == 0)
                    pb[(size_t)t * F_DIM + f] = acc[m][nf][reg];
                else
                    atomicAdd(&pb[(size_t)t * F_DIM + f], acc[m][nf][reg]);
            }
        }
    }
}

// Plain path: sum NKG partial slices, then indexed atomicAdd into out.
__global__ void scatter_sum_kernel(const float* __restrict__ partial,
                                   const int* __restrict__ tidx,
                                   float* __restrict__ out) {
    const int tid = threadIdx.x;
    const int t = blockIdx.x * 2 + (tid >> 7);
    const int f = tid & 127;
    const int g = tidx[t];
    const float* p = partial + (size_t)t * F_DIM + f;
    float s = 0.0f;
    #pragma unroll
    for (int kg = 0; kg < NKG; ++kg)
        s += p[(size_t)kg * (T_DIM * F_DIM)];
    atomicAdd(&out[(size_t)g * F_DIM + f], s);
}

// Fallback path: scatter sparse rows into d_out.
__global__ void scatter_kernel(const float* __restrict__ sparse,
                               const int* __restrict__ tidx,
                               float* __restrict__ out) {
    const int tid = threadIdx.x;
    const int t = blockIdx.x * 2 + (tid >> 7);
    const int f = tid & 127;
    const int g = tidx[t];
    atomicAdd(&out[(size_t)g * F_DIM + f], sparse[(size_t)t * F_DIM + f]);
}

extern "C" void kernel_launch(void* const* d_in, const int* in_sizes, int n_in,
                              void* d_out, int out_size, void* d_ws, size_t ws_size,
                              hipStream_t stream) {
    const float* feat0  = (const float*)d_in[0];
    const float* feat1  = (const float*)d_in[1];
    const float* feat2  = (const float*)d_in[2];
    const float* sph0   = (const float*)d_in[3];
    const float* sph1   = (const float*)d_in[4];
    const float* sph2   = (const float*)d_in[5];
    const float* radial = (const float*)d_in[6];
    const float* w1     = (const float*)d_in[7];
    const float* b1     = (const float*)d_in[8];
    const float* w2     = (const float*)d_in[9];
    const float* b2     = (const float*)d_in[10];
    const float* w3     = (const float*)d_in[11];
    const float* b3     = (const float*)d_in[12];
    const int*   tidx   = (const int*)d_in[13];
    float* out = (float*)d_out;

    // Common ws prefix: rbfws 3 MB | h2ws slot kept for layout stability
    float* rbfws  = (float*)d_ws;
    float* h2ws   = rbfws + 3 * A_DIM * RBF_DIM * F_DIM;

    // Plain path needs: prefix + Vt (4.5 MB) + partial (32 MB) ~= 41.7 MB
    const size_t plain_need =
        (size_t)(3 * A_DIM * RBF_DIM * F_DIM + 3 * A_DIM * F_DIM) * sizeof(float) +
        (size_t)F_DIM * VT_LD * sizeof(unsigned short) +
        (size_t)NKG * T_DIM * F_DIM * sizeof(float);
    const bool plain = (ws_size >= plain_need);

    mlp_fused_kernel<<<dim3(A_DIM / 32, 8, 3), 512, 0, stream>>>(
        feat0, w1, b1, w2, b2, w3, b3, rbfws);

    if (plain) {
        unsigned short* Vt = (unsigned short*)(h2ws + 3 * A_DIM * F_DIM);
        float* partial = (float*)(Vt + (size_t)F_DIM * VT_LD);
        build_vt_kernel<<<dim3(A_DIM, 9), 128, 0, stream>>>(feat0, feat1, feat2, rbfws, Vt);
        gemm_kernel<0><<<dim3(T_DIM / BT, A_DIM / 4), 256, 0, stream>>>(
            sph0, sph1, sph2, radial, Vt, partial, out, out_size / 4);
        scatter_sum_kernel<<<dim3(T_DIM / 2), 256, 0, stream>>>(partial, tidx, out);
    } else {
        // Fallback layout: rbfws | h2ws | sparse | Vt
        float* sparse = h2ws + 3 * A_DIM * F_DIM;
        unsigned short* Vt = (unsigned short*)(sparse + T_DIM * F_DIM);
        zero_kernel<<<2048, 256, 0, stream>>>((float4*)out, out_size / 4);
        hipMemsetAsync(sparse, 0, (size_t)T_DIM * F_DIM * sizeof(float), stream);
        build_vt_kernel<<<dim3(A_DIM, 9), 128, 0, stream>>>(feat0, feat1, feat2, rbfws, Vt);
        gemm_kernel<1><<<dim3(T_DIM / BT, A_DIM / 4), 256, 0, stream>>>(
            sph0, sph1, sph2, radial, Vt, sparse, out, out_size / 4);
        scatter_kernel<<<dim3(T_DIM / 2), 256, 0, stream>>>(sparse, tidx, out);
    }
}

// Round 18
// 65.274 us; speedup vs baseline: 1.4207x; 1.4207x over previous
//
#include <hip/hip_runtime.h>
#include <hip/hip_bf16.h>
#include <cstdint>
#include <cstddef>

#define A_DIM 128
#define T_DIM 2048
#define F_DIM 128
#define RBF_DIM 16
#define KDD 2048              // K-span per dd block (128 atoms x 16 rbf)
#define VT_LD 18432           // Vt row stride = 9 * KDD
#define NKG 32                // K-groups (A_DIM / 4) — R13 best config
#define BT 64                 // t-span per gemm block

typedef __attribute__((ext_vector_type(8))) short short8;
typedef __attribute__((ext_vector_type(4))) float f32x4;
typedef __attribute__((ext_vector_type(4))) unsigned int u32x4;

__device__ __forceinline__ float silu_f(float x) {
    return x / (1.0f + __expf(-x));
}

// f2bf (RNE bit-twiddle) for build_vt; gemm A-build uses v_cvt_pk_bf16_f32
// (also RNE). Do NOT swap for __float2bfloat16.
__device__ __forceinline__ unsigned short f2bf(float x) {
    union { float f; unsigned u; } v; v.f = x;
    unsigned r = v.u + 0x7FFFu + ((v.u >> 16) & 1u);
    return (unsigned short)(r >> 16);
}

// async global->LDS, 16 B per lane; LDS dest is wave-uniform base + lane*16.
__device__ __forceinline__ void gl_lds16(const void* g, void* l) {
    __builtin_amdgcn_global_load_lds(
        (const __attribute__((address_space(1))) void*)g,
        (__attribute__((address_space(3))) void*)l, 16, 0, 0);
}

// Grid-stride float4 zero (fallback path only; plain path zeroes in gemm).
__global__ void zero_kernel(float4* __restrict__ p, int n4) {
    const int stride = gridDim.x * blockDim.x;
    const float4 z = {0.f, 0.f, 0.f, 0.f};
    for (int i = blockIdx.x * blockDim.x + threadIdx.x; i < n4; i += stride)
        p[i] = z;
}

// grid (A/4, 3), block 512. h1/h2 MLP layers for 4 atoms (R4-exact, known good).
__global__ void mlp12_kernel(const float* __restrict__ feat0,
                             const float* __restrict__ w1, const float* __restrict__ b1,
                             const float* __restrict__ w2, const float* __restrict__ b2,
                             float* __restrict__ h2ws) {
    __shared__ float inv_s[4 * F_DIM];
    __shared__ float h_s[4 * F_DIM];
    const int i  = blockIdx.y;
    const int a0 = blockIdx.x * 4;
    const int tid = threadIdx.x;
    const int f  = tid & 127;
    const int la = tid >> 7;

    inv_s[tid] = feat0[(a0 + la) * F_DIM + f];
    __syncthreads();

    const float* w1i = w1 + (size_t)i * F_DIM * F_DIM;
    float x = b1[i * F_DIM + f];
    #pragma unroll 8
    for (int k = 0; k < F_DIM; ++k)
        x = fmaf(inv_s[la * F_DIM + k], w1i[k * F_DIM + f], x);
    h_s[tid] = silu_f(x);
    __syncthreads();

    const float* w2i = w2 + (size_t)i * F_DIM * F_DIM;
    float y = b2[i * F_DIM + f];
    #pragma unroll 8
    for (int k = 0; k < F_DIM; ++k)
        y = fmaf(h_s[la * F_DIM + k], w2i[k * F_DIM + f], y);
    h2ws[((size_t)i * A_DIM + a0 + la) * F_DIM + f] = silu_f(y);
}

// Layer 3, occupancy-correct: grid (A/16 = 8, 2048/128 = 16, 3) = 384 blocks
// (1.5 blocks/CU — whole machine busy), block 256, 8 KB LDS. Thread owns one
// col x 8 atoms (val[8], static). w3 per block = 64 KB slice -> 24 MB total
// (vs 96 MB in the R13 fused version whose ~39 us made it the LARGEST kernel;
// R17's 48KB-LDS/96-block retile was worse still — 68 us at 7.8% occupancy).
// Per-output k-ascending FMA chain identical -> bitwise-identical rbfws.
__global__ void mlp3_kernel(const float* __restrict__ h2ws,
                            const float* __restrict__ w3, const float* __restrict__ b3,
                            float* __restrict__ rbfws) {
    __shared__ float h2_s[16 * F_DIM];   // 8 KB
    const int i  = blockIdx.z;
    const int a0 = blockIdx.x * 16;
    const int c0 = blockIdx.y * 128;
    const int tid = threadIdx.x;

    #pragma unroll
    for (int j = 0; j < 8; ++j)
        h2_s[j * 256 + tid] = h2ws[((size_t)i * A_DIM + a0) * F_DIM + j * 256 + tid];
    __syncthreads();

    const int la = tid >> 7;             // 0..1 -> atoms la*8 .. la*8+7
    const int c  = c0 + (tid & 127);
    const float* w3i = w3 + (size_t)i * F_DIM * 2048;

    float val[8];
    const float b = b3[i * 2048 + c];
    #pragma unroll
    for (int a = 0; a < 8; ++a) val[a] = b;

    #pragma unroll 4
    for (int k = 0; k < F_DIM; ++k) {
        const float wv = w3i[(size_t)k * 2048 + c];
        #pragma unroll
        for (int a = 0; a < 8; ++a)
            val[a] = fmaf(h2_s[(la * 8 + a) * F_DIM + k], wv, val[a]);
    }

    const float inv_rbf = 0.25f;  // 1/sqrt(16)
    #pragma unroll
    for (int a = 0; a < 8; ++a)
        rbfws[((size_t)i * A_DIM + a0 + la * 8 + a) * 2048 + c] = val[a] * inv_rbf;
}

// Build Vt[f][k] bf16, k = dd*2048 + n*16 + r. (R4-exact.)
__global__ void build_vt_kernel(const float* __restrict__ feat0,
                                const float* __restrict__ feat1,
                                const float* __restrict__ feat2,
                                const float* __restrict__ rbfws,
                                unsigned short* __restrict__ Vt) {
    const int n  = blockIdx.x;
    const int dd = blockIdx.y;
    const int f  = threadIdx.x;

    int i, d;
    float fv;
    if (dd == 0)      { i = 0; d = 0;      fv = feat0[n * F_DIM + f]; }
    else if (dd < 4)  { i = 1; d = dd - 1; fv = feat1[(n * F_DIM + f) * 3 + d]; }
    else              { i = 2; d = dd - 4; fv = feat2[(n * F_DIM + f) * 5 + d]; }

    const float* rb = rbfws + ((size_t)(i * A_DIM + n) * RBF_DIM) * F_DIM + f;
    unsigned short* vp = Vt + (size_t)f * VT_LD + (size_t)dd * KDD + n * 16;
    #pragma unroll
    for (int r = 0; r < RBF_DIM; ++r)
        vp[r] = f2bf(fv * rb[(size_t)r * F_DIM]);
}

// MFMA GEMM — R13-exact (best measured). LDS-staged B + sph, monolithic
// dd-loop, zero-in-prologue, wave tile 32t x 64f.
// R15 LESSON: do NOT fuse heavy epilogue code here (regalloc collapse).
// grid (32 mt, 32 kg), block 256 = 4 waves in 2x2.
template<int MODE>
__global__ void __launch_bounds__(256) gemm_kernel(
        const float* __restrict__ sph0, const float* __restrict__ sph1,
        const float* __restrict__ sph2, const float* __restrict__ radial,
        const unsigned short* __restrict__ Vt,
        float* __restrict__ outbuf,
        float* __restrict__ dout, int out_n4) {
    __shared__ unsigned short b_s[F_DIM * 64];   // 16 KB: [f][chunk^(f&7)] 8-elem chunks
    __shared__ float sph_s[4 * BT];              // 1 KB: [nn][tt]

    const int tid  = threadIdx.x;
    const int lane = tid & 63;
    const int w    = tid >> 6;
    const int wr   = w >> 1;            // wave row (t)
    const int wc   = w & 1;             // wave col (f)
    const int t0   = blockIdx.x * BT + wr * 32;
    const int n0   = blockIdx.y * 4;
    const int kq   = lane >> 4;         // 0..3
    const int lf   = lane & 15;

    // Prologue: zero this block's slice of d_out (plain path only).
    if (MODE == 0) {
        const int bid = blockIdx.y * gridDim.x + blockIdx.x;     // 0..1023
        const float4 z = {0.f, 0.f, 0.f, 0.f};
        float4* zp = (float4*)dout;
        #pragma unroll
        for (int q = 0; q < 8; ++q) {
            const int idx = bid * 2048 + q * 256 + tid;
            if (idx < out_n4) zp[idx] = z;
        }
    }

    // radial is dd-invariant: preload once to regs.
    // k_local = 32*ks + 8*kq + j -> atom n0 + 2*ks + (kq>>1), r = (kq&1)*8 + j.
    f32x4 rad[2][2][2];
    #pragma unroll
    for (int m = 0; m < 2; ++m) {
        const int t = t0 + 16 * m + lf;
        #pragma unroll
        for (int ks = 0; ks < 2; ++ks) {
            const int n = n0 + 2 * ks + (kq >> 1);
            const float* rp = radial + ((size_t)n * T_DIM + t) * 16 + (kq & 1) * 8;
            rad[m][ks][0] = *reinterpret_cast<const f32x4*>(rp);
            rad[m][ks][1] = *reinterpret_cast<const f32x4*>(rp + 4);
        }
    }

    // B staging source: per issue q, row f = q*32 + tid/8, chunk c' = (tid%8)^((tid/8)&7)
    const int fs_row = tid >> 3;
    const int cs     = (tid & 7) ^ ((tid >> 3) & 7);
    const unsigned short* gsrc0 = Vt + (size_t)fs_row * VT_LD + n0 * 16 + cs * 8;
    // sph staging: thread tid -> sph_s[nn*BT+tt]
    const int nn_s = tid >> 6;
    const int tt_s = tid & 63;
    const size_t sph_tbase = (size_t)(n0 + nn_s) * T_DIM + blockIdx.x * BT + tt_s;

    f32x4 acc[2][4];
    #pragma unroll
    for (int m = 0; m < 2; ++m)
        #pragma unroll
        for (int nf = 0; nf < 4; ++nf)
            acc[m][nf] = (f32x4){0.f, 0.f, 0.f, 0.f};

    #pragma unroll 1
    for (int dd = 0; dd < 9; ++dd) {
        const float* sp; int smul, soff;
        if (dd == 0)     { sp = sph0; smul = 1; soff = 0; }
        else if (dd < 4) { sp = sph1; smul = 3; soff = dd - 1; }
        else             { sp = sph2; smul = 5; soff = dd - 4; }

        __syncthreads();   // previous iteration done reading LDS

        // stage B-tile: 4 issues x (256 lanes x 16 B) = 16 KB, linear LDS dest
        const size_t koff = (size_t)dd * KDD;
        #pragma unroll
        for (int q = 0; q < 4; ++q) {
            const unsigned short* gp = gsrc0 + koff + (size_t)(q * 32) * VT_LD;
            void* lp = (void*)((char*)b_s + q * 4096 + w * 1024);
            gl_lds16(gp, lp);
        }
        // stage sph tile (256 floats)
        sph_s[tid] = sp[sph_tbase * smul + soff];

        __syncthreads();   // drains vmcnt+lgkmcnt before s_barrier

        // B-fragments from LDS (swizzled read): chunk cw = 4*ks+kq at row f
        short8 bfr[2][4];
        #pragma unroll
        for (int ks = 0; ks < 2; ++ks) {
            #pragma unroll
            for (int nf = 0; nf < 4; ++nf) {
                const int f = wc * 64 + 16 * nf + lf;
                const int byte = f * 128 + (((ks * 4 + kq) ^ (lf & 7)) * 16);
                bfr[ks][nf] = *reinterpret_cast<const short8*>((const char*)b_s + byte);
            }
        }

        // A-fragments: 8 products + 4 v_cvt_pk_bf16_f32 (RNE), then MFMAs.
        #pragma unroll
        for (int m = 0; m < 2; ++m) {
            #pragma unroll
            for (int ks = 0; ks < 2; ++ks) {
                const float s = sph_s[(2 * ks + (kq >> 1)) * BT + wr * 32 + 16 * m + lf];
                unsigned int d0, d1, d2, d3;
                asm("v_cvt_pk_bf16_f32 %0, %1, %2" : "=v"(d0)
                    : "v"(s * rad[m][ks][0][0]), "v"(s * rad[m][ks][0][1]));
                asm("v_cvt_pk_bf16_f32 %0, %1, %2" : "=v"(d1)
                    : "v"(s * rad[m][ks][0][2]), "v"(s * rad[m][ks][0][3]));
                asm("v_cvt_pk_bf16_f32 %0, %1, %2" : "=v"(d2)
                    : "v"(s * rad[m][ks][1][0]), "v"(s * rad[m][ks][1][1]));
                asm("v_cvt_pk_bf16_f32 %0, %1, %2" : "=v"(d3)
                    : "v"(s * rad[m][ks][1][2]), "v"(s * rad[m][ks][1][3]));
                union { u32x4 u; short8 s8; } au;
                au.u = (u32x4){d0, d1, d2, d3};
                #pragma unroll
                for (int nf = 0; nf < 4; ++nf)
                    acc[m][nf] = __builtin_amdgcn_mfma_f32_16x16x32_bf16(
                        au.s8, bfr[ks][nf], acc[m][nf], 0, 0, 0);
            }
        }
    }

    // Epilogue. C/D layout col=lane&15, row=(lane>>4)*4+reg (HW-verified in R4).
    float* pb = (MODE == 0)
        ? outbuf + (size_t)blockIdx.y * (T_DIM * F_DIM)   // own slice, plain stores
        : outbuf;                                          // shared, atomics
    #pragma unroll
    for (int m = 0; m < 2; ++m) {
        #pragma unroll
        for (int nf = 0; nf < 4; ++nf) {
            const int f = wc * 64 + 16 * nf + lf;
            #pragma unroll
            for (int reg = 0; reg < 4; ++reg) {
                const int t = t0 + 16 * m + 4 * kq + reg;
                if (MODE == 0)
                    pb[(size_t)t * F_DIM + f] = acc[m][nf][reg];
                else
                    atomicAdd(&pb[(size_t)t * F_DIM + f], acc[m][nf][reg]);
            }
        }
    }
}

// Plain path: sum NKG partial slices, then indexed atomicAdd into out.
__global__ void scatter_sum_kernel(const float* __restrict__ partial,
                                   const int* __restrict__ tidx,
                                   float* __restrict__ out) {
    const int tid = threadIdx.x;
    const int t = blockIdx.x * 2 + (tid >> 7);
    const int f = tid & 127;
    const int g = tidx[t];
    const float* p = partial + (size_t)t * F_DIM + f;
    float s = 0.0f;
    #pragma unroll
    for (int kg = 0; kg < NKG; ++kg)
        s += p[(size_t)kg * (T_DIM * F_DIM)];
    atomicAdd(&out[(size_t)g * F_DIM + f], s);
}

// Fallback path: scatter sparse rows into d_out.
__global__ void scatter_kernel(const float* __restrict__ sparse,
                               const int* __restrict__ tidx,
                               float* __restrict__ out) {
    const int tid = threadIdx.x;
    const int t = blockIdx.x * 2 + (tid >> 7);
    const int f = tid & 127;
    const int g = tidx[t];
    atomicAdd(&out[(size_t)g * F_DIM + f], sparse[(size_t)t * F_DIM + f]);
}

extern "C" void kernel_launch(void* const* d_in, const int* in_sizes, int n_in,
                              void* d_out, int out_size, void* d_ws, size_t ws_size,
                              hipStream_t stream) {
    const float* feat0  = (const float*)d_in[0];
    const float* feat1  = (const float*)d_in[1];
    const float* feat2  = (const float*)d_in[2];
    const float* sph0   = (const float*)d_in[3];
    const float* sph1   = (const float*)d_in[4];
    const float* sph2   = (const float*)d_in[5];
    const float* radial = (const float*)d_in[6];
    const float* w1     = (const float*)d_in[7];
    const float* b1     = (const float*)d_in[8];
    const float* w2     = (const float*)d_in[9];
    const float* b2     = (const float*)d_in[10];
    const float* w3     = (const float*)d_in[11];
    const float* b3     = (const float*)d_in[12];
    const int*   tidx   = (const int*)d_in[13];
    float* out = (float*)d_out;

    // ws: rbfws 3 MB | h2ws 192 KB | Vt 4.5 MB | partial 32 MB
    float* rbfws  = (float*)d_ws;
    float* h2ws   = rbfws + 3 * A_DIM * RBF_DIM * F_DIM;

    const size_t plain_need =
        (size_t)(3 * A_DIM * RBF_DIM * F_DIM + 3 * A_DIM * F_DIM) * sizeof(float) +
        (size_t)F_DIM * VT_LD * sizeof(unsigned short) +
        (size_t)NKG * T_DIM * F_DIM * sizeof(float);
    const bool plain = (ws_size >= plain_need);

    mlp12_kernel<<<dim3(A_DIM / 4, 3), 512, 0, stream>>>(feat0, w1, b1, w2, b2, h2ws);
    mlp3_kernel<<<dim3(A_DIM / 16, 16, 3), 256, 0, stream>>>(h2ws, w3, b3, rbfws);

    if (plain) {
        unsigned short* Vt = (unsigned short*)(h2ws + 3 * A_DIM * F_DIM);
        float* partial = (float*)(Vt + (size_t)F_DIM * VT_LD);
        build_vt_kernel<<<dim3(A_DIM, 9), 128, 0, stream>>>(feat0, feat1, feat2, rbfws, Vt);
        gemm_kernel<0><<<dim3(T_DIM / BT, A_DIM / 4), 256, 0, stream>>>(
            sph0, sph1, sph2, radial, Vt, partial, out, out_size / 4);
        scatter_sum_kernel<<<dim3(T_DIM / 2), 256, 0, stream>>>(partial, tidx, out);
    } else {
        // Fallback layout: rbfws | h2ws | sparse | Vt
        float* sparse = h2ws + 3 * A_DIM * F_DIM;
        unsigned short* Vt = (unsigned short*)(sparse + T_DIM * F_DIM);
        zero_kernel<<<2048, 256, 0, stream>>>((float4*)out, out_size / 4);
        hipMemsetAsync(sparse, 0, (size_t)T_DIM * F_DIM * sizeof(float), stream);
        build_vt_kernel<<<dim3(A_DIM, 9), 128, 0, stream>>>(feat0, feat1, feat2, rbfws, Vt);
        gemm_kernel<1><<<dim3(T_DIM / BT, A_DIM / 4), 256, 0, stream>>>(
            sph0, sph1, sph2, radial, Vt, sparse, out, out_size / 4);
        scatter_kernel<<<dim3(T_DIM / 2), 256, 0, stream>>>(sparse, tidx, out);
    }
}

// Round 19
// 63.757 us; speedup vs baseline: 1.4545x; 1.0238x over previous
//
#include <hip/hip_runtime.h>
#include <hip/hip_bf16.h>
#include <cstdint>
#include <cstddef>

#define A_DIM 128
#define T_DIM 2048
#define F_DIM 128
#define RBF_DIM 16
#define KDD 2048              // K-span per dd block (128 atoms x 16 rbf)
#define VT_LD 18432           // Vt row stride = 9 * KDD
#define NKG 32                // K-groups (A_DIM / 4) — R13 best config
#define BT 64                 // t-span per gemm block

typedef __attribute__((ext_vector_type(8))) short short8;
typedef __attribute__((ext_vector_type(4))) float f32x4;
typedef __attribute__((ext_vector_type(4))) unsigned int u32x4;

__device__ __forceinline__ float silu_f(float x) {
    return x / (1.0f + __expf(-x));
}

// f2bf (RNE bit-twiddle) for build_vt; gemm A-build uses v_cvt_pk_bf16_f32
// (also RNE). Do NOT swap for __float2bfloat16.
__device__ __forceinline__ unsigned short f2bf(float x) {
    union { float f; unsigned u; } v; v.f = x;
    unsigned r = v.u + 0x7FFFu + ((v.u >> 16) & 1u);
    return (unsigned short)(r >> 16);
}

// async global->LDS, 16 B per lane; LDS dest is wave-uniform base + lane*16.
__device__ __forceinline__ void gl_lds16(const void* g, void* l) {
    __builtin_amdgcn_global_load_lds(
        (const __attribute__((address_space(1))) void*)g,
        (__attribute__((address_space(3))) void*)l, 16, 0, 0);
}

// Grid-stride float4 zero (fallback path only; plain path zeroes in gemm).
__global__ void zero_kernel(float4* __restrict__ p, int n4) {
    const int stride = gridDim.x * blockDim.x;
    const float4 z = {0.f, 0.f, 0.f, 0.f};
    for (int i = blockIdx.x * blockDim.x + threadIdx.x; i < n4; i += stride)
        p[i] = z;
}

// grid (A/4, 3), block 512. h1/h2 MLP layers for 4 atoms (R4-exact, known good).
__global__ void mlp12_kernel(const float* __restrict__ feat0,
                             const float* __restrict__ w1, const float* __restrict__ b1,
                             const float* __restrict__ w2, const float* __restrict__ b2,
                             float* __restrict__ h2ws) {
    __shared__ float inv_s[4 * F_DIM];
    __shared__ float h_s[4 * F_DIM];
    const int i  = blockIdx.y;
    const int a0 = blockIdx.x * 4;
    const int tid = threadIdx.x;
    const int f  = tid & 127;
    const int la = tid >> 7;

    inv_s[tid] = feat0[(a0 + la) * F_DIM + f];
    __syncthreads();

    const float* w1i = w1 + (size_t)i * F_DIM * F_DIM;
    float x = b1[i * F_DIM + f];
    #pragma unroll 8
    for (int k = 0; k < F_DIM; ++k)
        x = fmaf(inv_s[la * F_DIM + k], w1i[k * F_DIM + f], x);
    h_s[tid] = silu_f(x);
    __syncthreads();

    const float* w2i = w2 + (size_t)i * F_DIM * F_DIM;
    float y = b2[i * F_DIM + f];
    #pragma unroll 8
    for (int k = 0; k < F_DIM; ++k)
        y = fmaf(h_s[la * F_DIM + k], w2i[k * F_DIM + f], y);
    h2ws[((size_t)i * A_DIM + a0 + la) * F_DIM + f] = silu_f(y);
}

// Layer 3, ILP+TLP version. R13-fused (96 blocks, 0.375/CU) and R18's mlp3
// (384 blocks, 8 LDS reads/FMA-octet) both measured ~38-40 us — LATENCY-bound,
// not BW-bound (byte cuts 96->24 MB changed nothing). This version:
// grid (A/8 = 16, 2048/128 = 16, 3) = 768 blocks (3 waves/SIMD), block 256,
// 4 KB LDS. Thread = 1 atom x 4 cols: per k = 1 float4 w3 load + 1 LDS
// broadcast + 4 FMA, unroll 4 -> 4 independent 16 B loads in flight.
// Per-output k-ascending FMA chain identical -> bitwise-identical rbfws.
__global__ void mlp3_kernel(const float* __restrict__ h2ws,
                            const float* __restrict__ w3, const float* __restrict__ b3,
                            float* __restrict__ rbfws) {
    __shared__ float h2_s[8 * F_DIM];    // 4 KB
    const int i  = blockIdx.z;
    const int a0 = blockIdx.x * 8;
    const int c0 = blockIdx.y * 128;
    const int tid = threadIdx.x;

    #pragma unroll
    for (int j = 0; j < 4; ++j)
        h2_s[j * 256 + tid] = h2ws[((size_t)i * A_DIM + a0) * F_DIM + j * 256 + tid];
    __syncthreads();

    const int a = tid >> 5;              // 0..7 (atom within tile)
    const int c = c0 + (tid & 31) * 4;   // float4 column
    const float* w3i = w3 + (size_t)i * F_DIM * 2048;

    float val[4];
    #pragma unroll
    for (int cc = 0; cc < 4; ++cc)
        val[cc] = b3[i * 2048 + c + cc];

    #pragma unroll 4
    for (int k = 0; k < F_DIM; ++k) {
        const float4 w = *reinterpret_cast<const float4*>(&w3i[(size_t)k * 2048 + c]);
        const float h = h2_s[a * F_DIM + k];
        val[0] = fmaf(h, w.x, val[0]);
        val[1] = fmaf(h, w.y, val[1]);
        val[2] = fmaf(h, w.z, val[2]);
        val[3] = fmaf(h, w.w, val[3]);
    }

    const float inv_rbf = 0.25f;  // 1/sqrt(16)
    float4 o;
    o.x = val[0] * inv_rbf;
    o.y = val[1] * inv_rbf;
    o.z = val[2] * inv_rbf;
    o.w = val[3] * inv_rbf;
    *reinterpret_cast<float4*>(&rbfws[((size_t)i * A_DIM + a0 + a) * 2048 + c]) = o;
}

// Build Vt[f][k] bf16, k = dd*2048 + n*16 + r. (R4-exact.)
__global__ void build_vt_kernel(const float* __restrict__ feat0,
                                const float* __restrict__ feat1,
                                const float* __restrict__ feat2,
                                const float* __restrict__ rbfws,
                                unsigned short* __restrict__ Vt) {
    const int n  = blockIdx.x;
    const int dd = blockIdx.y;
    const int f  = threadIdx.x;

    int i, d;
    float fv;
    if (dd == 0)      { i = 0; d = 0;      fv = feat0[n * F_DIM + f]; }
    else if (dd < 4)  { i = 1; d = dd - 1; fv = feat1[(n * F_DIM + f) * 3 + d]; }
    else              { i = 2; d = dd - 4; fv = feat2[(n * F_DIM + f) * 5 + d]; }

    const float* rb = rbfws + ((size_t)(i * A_DIM + n) * RBF_DIM) * F_DIM + f;
    unsigned short* vp = Vt + (size_t)f * VT_LD + (size_t)dd * KDD + n * 16;
    #pragma unroll
    for (int r = 0; r < RBF_DIM; ++r)
        vp[r] = f2bf(fv * rb[(size_t)r * F_DIM]);
}

// MFMA GEMM — R13-exact (best measured). LDS-staged B + sph, monolithic
// dd-loop, zero-in-prologue, wave tile 32t x 64f.
// R15 LESSON: do NOT fuse heavy epilogue code here (regalloc collapse).
// grid (32 mt, 32 kg), block 256 = 4 waves in 2x2.
template<int MODE>
__global__ void __launch_bounds__(256) gemm_kernel(
        const float* __restrict__ sph0, const float* __restrict__ sph1,
        const float* __restrict__ sph2, const float* __restrict__ radial,
        const unsigned short* __restrict__ Vt,
        float* __restrict__ outbuf,
        float* __restrict__ dout, int out_n4) {
    __shared__ unsigned short b_s[F_DIM * 64];   // 16 KB: [f][chunk^(f&7)] 8-elem chunks
    __shared__ float sph_s[4 * BT];              // 1 KB: [nn][tt]

    const int tid  = threadIdx.x;
    const int lane = tid & 63;
    const int w    = tid >> 6;
    const int wr   = w >> 1;            // wave row (t)
    const int wc   = w & 1;             // wave col (f)
    const int t0   = blockIdx.x * BT + wr * 32;
    const int n0   = blockIdx.y * 4;
    const int kq   = lane >> 4;         // 0..3
    const int lf   = lane & 15;

    // Prologue: zero this block's slice of d_out (plain path only).
    if (MODE == 0) {
        const int bid = blockIdx.y * gridDim.x + blockIdx.x;     // 0..1023
        const float4 z = {0.f, 0.f, 0.f, 0.f};
        float4* zp = (float4*)dout;
        #pragma unroll
        for (int q = 0; q < 8; ++q) {
            const int idx = bid * 2048 + q * 256 + tid;
            if (idx < out_n4) zp[idx] = z;
        }
    }

    // radial is dd-invariant: preload once to regs.
    // k_local = 32*ks + 8*kq + j -> atom n0 + 2*ks + (kq>>1), r = (kq&1)*8 + j.
    f32x4 rad[2][2][2];
    #pragma unroll
    for (int m = 0; m < 2; ++m) {
        const int t = t0 + 16 * m + lf;
        #pragma unroll
        for (int ks = 0; ks < 2; ++ks) {
            const int n = n0 + 2 * ks + (kq >> 1);
            const float* rp = radial + ((size_t)n * T_DIM + t) * 16 + (kq & 1) * 8;
            rad[m][ks][0] = *reinterpret_cast<const f32x4*>(rp);
            rad[m][ks][1] = *reinterpret_cast<const f32x4*>(rp + 4);
        }
    }

    // B staging source: per issue q, row f = q*32 + tid/8, chunk c' = (tid%8)^((tid/8)&7)
    const int fs_row = tid >> 3;
    const int cs     = (tid & 7) ^ ((tid >> 3) & 7);
    const unsigned short* gsrc0 = Vt + (size_t)fs_row * VT_LD + n0 * 16 + cs * 8;
    // sph staging: thread tid -> sph_s[nn*BT+tt]
    const int nn_s = tid >> 6;
    const int tt_s = tid & 63;
    const size_t sph_tbase = (size_t)(n0 + nn_s) * T_DIM + blockIdx.x * BT + tt_s;

    f32x4 acc[2][4];
    #pragma unroll
    for (int m = 0; m < 2; ++m)
        #pragma unroll
        for (int nf = 0; nf < 4; ++nf)
            acc[m][nf] = (f32x4){0.f, 0.f, 0.f, 0.f};

    #pragma unroll 1
    for (int dd = 0; dd < 9; ++dd) {
        const float* sp; int smul, soff;
        if (dd == 0)     { sp = sph0; smul = 1; soff = 0; }
        else if (dd < 4) { sp = sph1; smul = 3; soff = dd - 1; }
        else             { sp = sph2; smul = 5; soff = dd - 4; }

        __syncthreads();   // previous iteration done reading LDS

        // stage B-tile: 4 issues x (256 lanes x 16 B) = 16 KB, linear LDS dest
        const size_t koff = (size_t)dd * KDD;
        #pragma unroll
        for (int q = 0; q < 4; ++q) {
            const unsigned short* gp = gsrc0 + koff + (size_t)(q * 32) * VT_LD;
            void* lp = (void*)((char*)b_s + q * 4096 + w * 1024);
            gl_lds16(gp, lp);
        }
        // stage sph tile (256 floats)
        sph_s[tid] = sp[sph_tbase * smul + soff];

        __syncthreads();   // drains vmcnt+lgkmcnt before s_barrier

        // B-fragments from LDS (swizzled read): chunk cw = 4*ks+kq at row f
        short8 bfr[2][4];
        #pragma unroll
        for (int ks = 0; ks < 2; ++ks) {
            #pragma unroll
            for (int nf = 0; nf < 4; ++nf) {
                const int f = wc * 64 + 16 * nf + lf;
                const int byte = f * 128 + (((ks * 4 + kq) ^ (lf & 7)) * 16);
                bfr[ks][nf] = *reinterpret_cast<const short8*>((const char*)b_s + byte);
            }
        }

        // A-fragments: 8 products + 4 v_cvt_pk_bf16_f32 (RNE), then MFMAs.
        #pragma unroll
        for (int m = 0; m < 2; ++m) {
            #pragma unroll
            for (int ks = 0; ks < 2; ++ks) {
                const float s = sph_s[(2 * ks + (kq >> 1)) * BT + wr * 32 + 16 * m + lf];
                unsigned int d0, d1, d2, d3;
                asm("v_cvt_pk_bf16_f32 %0, %1, %2" : "=v"(d0)
                    : "v"(s * rad[m][ks][0][0]), "v"(s * rad[m][ks][0][1]));
                asm("v_cvt_pk_bf16_f32 %0, %1, %2" : "=v"(d1)
                    : "v"(s * rad[m][ks][0][2]), "v"(s * rad[m][ks][0][3]));
                asm("v_cvt_pk_bf16_f32 %0, %1, %2" : "=v"(d2)
                    : "v"(s * rad[m][ks][1][0]), "v"(s * rad[m][ks][1][1]));
                asm("v_cvt_pk_bf16_f32 %0, %1, %2" : "=v"(d3)
                    : "v"(s * rad[m][ks][1][2]), "v"(s * rad[m][ks][1][3]));
                union { u32x4 u; short8 s8; } au;
                au.u = (u32x4){d0, d1, d2, d3};
                #pragma unroll
                for (int nf = 0; nf < 4; ++nf)
                    acc[m][nf] = __builtin_amdgcn_mfma_f32_16x16x32_bf16(
                        au.s8, bfr[ks][nf], acc[m][nf], 0, 0, 0);
            }
        }
    }

    // Epilogue. C/D layout col=lane&15, row=(lane>>4)*4+reg (HW-verified in R4).
    float* pb = (MODE == 0)
        ? outbuf + (size_t)blockIdx.y * (T_DIM * F_DIM)   // own slice, plain stores
        : outbuf;                                          // shared, atomics
    #pragma unroll
    for (int m = 0; m < 2; ++m) {
        #pragma unroll
        for (int nf = 0; nf < 4; ++nf) {
            const int f = wc * 64 + 16 * nf + lf;
            #pragma unroll
            for (int reg = 0; reg < 4; ++reg) {
                const int t = t0 + 16 * m + 4 * kq + reg;
                if (MODE == 0)
                    pb[(size_t)t * F_DIM + f] = acc[m][nf][reg];
                else
                    atomicAdd(&pb[(size_t)t * F_DIM + f], acc[m][nf][reg]);
            }
        }
    }
}

// Plain path: sum NKG partial slices, then indexed atomicAdd into out.
__global__ void scatter_sum_kernel(const float* __restrict__ partial,
                                   const int* __restrict__ tidx,
                                   float* __restrict__ out) {
    const int tid = threadIdx.x;
    const int t = blockIdx.x * 2 + (tid >> 7);
    const int f = tid & 127;
    const int g = tidx[t];
    const float* p = partial + (size_t)t * F_DIM + f;
    float s = 0.0f;
    #pragma unroll
    for (int kg = 0; kg < NKG; ++kg)
        s += p[(size_t)kg * (T_DIM * F_DIM)];
    atomicAdd(&out[(size_t)g * F_DIM + f], s);
}

// Fallback path: scatter sparse rows into d_out.
__global__ void scatter_kernel(const float* __restrict__ sparse,
                               const int* __restrict__ tidx,
                               float* __restrict__ out) {
    const int tid = threadIdx.x;
    const int t = blockIdx.x * 2 + (tid >> 7);
    const int f = tid & 127;
    const int g = tidx[t];
    atomicAdd(&out[(size_t)g * F_DIM + f], sparse[(size_t)t * F_DIM + f]);
}

extern "C" void kernel_launch(void* const* d_in, const int* in_sizes, int n_in,
                              void* d_out, int out_size, void* d_ws, size_t ws_size,
                              hipStream_t stream) {
    const float* feat0  = (const float*)d_in[0];
    const float* feat1  = (const float*)d_in[1];
    const float* feat2  = (const float*)d_in[2];
    const float* sph0   = (const float*)d_in[3];
    const float* sph1   = (const float*)d_in[4];
    const float* sph2   = (const float*)d_in[5];
    const float* radial = (const float*)d_in[6];
    const float* w1     = (const float*)d_in[7];
    const float* b1     = (const float*)d_in[8];
    const float* w2     = (const float*)d_in[9];
    const float* b2     = (const float*)d_in[10];
    const float* w3     = (const float*)d_in[11];
    const float* b3     = (const float*)d_in[12];
    const int*   tidx   = (const int*)d_in[13];
    float* out = (float*)d_out;

    // ws: rbfws 3 MB | h2ws 192 KB | Vt 4.5 MB | partial 32 MB
    float* rbfws  = (float*)d_ws;
    float* h2ws   = rbfws + 3 * A_DIM * RBF_DIM * F_DIM;

    const size_t plain_need =
        (size_t)(3 * A_DIM * RBF_DIM * F_DIM + 3 * A_DIM * F_DIM) * sizeof(float) +
        (size_t)F_DIM * VT_LD * sizeof(unsigned short) +
        (size_t)NKG * T_DIM * F_DIM * sizeof(float);
    const bool plain = (ws_size >= plain_need);

    mlp12_kernel<<<dim3(A_DIM / 4, 3), 512, 0, stream>>>(feat0, w1, b1, w2, b2, h2ws);
    mlp3_kernel<<<dim3(A_DIM / 8, 16, 3), 256, 0, stream>>>(h2ws, w3, b3, rbfws);

    if (plain) {
        unsigned short* Vt = (unsigned short*)(h2ws + 3 * A_DIM * F_DIM);
        float* partial = (float*)(Vt + (size_t)F_DIM * VT_LD);
        build_vt_kernel<<<dim3(A_DIM, 9), 128, 0, stream>>>(feat0, feat1, feat2, rbfws, Vt);
        gemm_kernel<0><<<dim3(T_DIM / BT, A_DIM / 4), 256, 0, stream>>>(
            sph0, sph1, sph2, radial, Vt, partial, out, out_size / 4);
        scatter_sum_kernel<<<dim3(T_DIM / 2), 256, 0, stream>>>(partial, tidx, out);
    } else {
        // Fallback layout: rbfws | h2ws | sparse | Vt
        float* sparse = h2ws + 3 * A_DIM * F_DIM;
        unsigned short* Vt = (unsigned short*)(sparse + T_DIM * F_DIM);
        zero_kernel<<<2048, 256, 0, stream>>>((float4*)out, out_size / 4);
        hipMemsetAsync(sparse, 0, (size_t)T_DIM * F_DIM * sizeof(float), stream);
        build_vt_kernel<<<dim3(A_DIM, 9), 128, 0, stream>>>(feat0, feat1, feat2, rbfws, Vt);
        gemm_kernel<1><<<dim3(T_DIM / BT, A_DIM / 4), 256, 0, stream>>>(
            sph0, sph1, sph2, radial, Vt, sparse, out, out_size / 4);
        scatter_kernel<<<dim3(T_DIM / 2), 256, 0, stream>>>(sparse, tidx, out);
    }
}